// Round 10
// baseline (114.949 us; speedup 1.0000x reference)
//
#include <hip/hip_runtime.h>

// Sparse generative transposed-conv LSTM decoder (3 timesteps).
// R10: R9 step structure (bare barriers, 2-deep register staging, LDS-coalesced
// stores) + merged [h|c|x_next] 384B state rows built by the PRODUCER step
// (x_next[j] read coalesced in store phase, hidden under MFMA) + ballot-ordered
// scatter (j-sorted within 256-row chunks -> DRAM-local stores).
// Dispatches: memset(96B), prep_w, scatter, 3x step = 6.

#define KNUM 8
#define TM 32
#define STEP_THREADS 256

typedef __attribute__((ext_vector_type(8))) _Float16 f16x8;
typedef __attribute__((ext_vector_type(4))) float f32x4;

__device__ __forceinline__ float fsig(float x) {
  return __builtin_amdgcn_rcpf(1.0f + __expf(-x));
}
__device__ __forceinline__ float ftanh_(float x) {
  float e = __expf(2.0f * x);
  return 1.0f - 2.0f * __builtin_amdgcn_rcpf(e + 1.0f);
}
__device__ __forceinline__ f16x8 to_h8(float4 a, float4 b) {
  f16x8 r;
  r[0] = (_Float16)a.x; r[1] = (_Float16)a.y; r[2] = (_Float16)a.z; r[3] = (_Float16)a.w;
  r[4] = (_Float16)b.x; r[5] = (_Float16)b.y; r[6] = (_Float16)b.z; r[7] = (_Float16)b.w;
  return r;
}

// ---- prep: weights transpose+cast only (~2.3 MB) ----
__global__ void prep_w_kernel(const float* __restrict__ Wi, const float* __restrict__ Wh,
                              const float* __restrict__ Wc,
                              _Float16* __restrict__ WgT, _Float16* __restrict__ WcT) {
  int tid = blockIdx.x * blockDim.x + threadIdx.x;
  int stride = gridDim.x * blockDim.x;
  // WgT[k][co][ci]: ci<64 -> W_h, else W_i (f16)
  for (int idx = tid; idx < KNUM * 256 * 128; idx += stride) {
    int k  = idx >> 15;
    int co = (idx >> 7) & 255;
    int ci = idx & 127;
    float v = (ci < 64) ? Wh[(k * 64 + ci) * 256 + co]
                        : Wi[(k * 64 + ci - 64) * 256 + co];
    WgT[idx] = (_Float16)v;
  }
  for (int idx = tid; idx < KNUM * 64 * 64; idx += stride) {
    int k  = idx >> 12;
    int co = (idx >> 6) & 63;
    int ci = idx & 63;
    WcT[idx] = (_Float16)Wc[(k * 64 + ci) * 64 + co];
  }
}

// ---- ballot-ordered scatter: 256 elems/block, exact j-order within block ----
__global__ void scatter_all_kernel(const int* __restrict__ k0, const int* __restrict__ p0, int n0,
                                   int2* __restrict__ op0, int cap0,
                                   const int* __restrict__ k1, const int* __restrict__ p1, int n1,
                                   int2* __restrict__ op1, int cap1,
                                   const int* __restrict__ k2, const int* __restrict__ p2, int n2,
                                   int2* __restrict__ op2, int cap2,
                                   int* __restrict__ cursor, int nb0, int nb1) {
  int b = blockIdx.x;
  int seg, rb;
  if (b < nb0)            { seg = 0; rb = b; }
  else if (b < nb0 + nb1) { seg = 1; rb = b - nb0; }
  else                    { seg = 2; rb = b - nb0 - nb1; }
  const int* kp = seg == 0 ? k0 : seg == 1 ? k1 : k2;
  const int* pp = seg == 0 ? p0 : seg == 1 ? p1 : p2;
  int n   = seg == 0 ? n0 : seg == 1 ? n1 : n2;
  int cap = seg == 0 ? cap0 : seg == 1 ? cap1 : cap2;
  int2* op = seg == 0 ? op0 : seg == 1 ? op1 : op2;
  int* cur = cursor + seg * KNUM;

  const int i = rb * 256 + (int)threadIdx.x;
  const int lane = threadIdx.x & 63;
  const int wid  = threadIdx.x >> 6;
  int myk = (i < n) ? kp[i] : KNUM;

  __shared__ int wcnt[4][KNUM];
  __shared__ int kbase[KNUM];
  int myrank = 0;
#pragma unroll
  for (int k = 0; k < KNUM; ++k) {
    unsigned long long m = __ballot(myk == k);
    if (myk == k) myrank = __popcll(m & ((1ull << lane) - 1ull));
    if (lane == 0) wcnt[wid][k] = __popcll(m);
  }
  __syncthreads();
  if (threadIdx.x < KNUM) {
    int tot = wcnt[0][threadIdx.x] + wcnt[1][threadIdx.x] +
              wcnt[2][threadIdx.x] + wcnt[3][threadIdx.x];
    kbase[threadIdx.x] = tot ? atomicAdd(&cur[threadIdx.x], tot) : 0;
  }
  __syncthreads();
  if (myk < KNUM) {
    int woff = 0;
    for (int w = 0; w < wid; ++w) woff += wcnt[w][myk];
    // chunk base order nondeterministic; output row-indexed -> deterministic
    op[myk * cap + kbase[myk] + woff + myrank] = make_int2(i, pp[i]);
  }
}

// ---- step kernel ----
// hc rows (produced/consumed): [h(64) | c(64) | x_next(64)] f16 = 384 B.
// FIRST gathers x0 (f32) directly; !FIRST gathers ONE 384B region per row.
// Producer steps (!LAST) read x_next[j] coalesced (prefetched under MFMA) and
// pack it into the merged output row.
template <bool FIRST, bool LAST>
__global__ __launch_bounds__(STEP_THREADS)
void lstm_step_kernel(const float* __restrict__ xf32, const _Float16* __restrict__ hc_in,
                      const float* __restrict__ xnext,
                      const int2* __restrict__ op, const int* __restrict__ counts, int cap,
                      const _Float16* __restrict__ WgT, const _Float16* __restrict__ WcT,
                      float* __restrict__ out32, _Float16* __restrict__ hc_out, int bpk) {
  __shared__ __align__(16) _Float16 A[TM][136];   // [h(0:64)|x(64:128)] + pad
  __shared__ __align__(16) _Float16 Cg[TM][72];
  __shared__ int jidx[TM];
  __shared__ __align__(16) char Obuf[9216];       // LAST: f32[32][68]; else 2x f16[32][72]
  float (*O32)[68] = (float(*)[68])Obuf;
  _Float16 (*Oh)[72] = (_Float16(*)[72])Obuf;
  _Float16 (*Oc)[72] = (_Float16(*)[72])(Obuf + 32 * 72 * 2);

  const int kb = blockIdx.x & 7;
  const int bi = blockIdx.x >> 3;
  const int cnt = counts[kb];
  const int off = kb * cap;
  const int ntiles = (cnt + TM - 1) / TM;
  if (bi >= ntiles || cnt == 0) return;

  const int tid  = threadIdx.x;
  const int lane = tid & 63;
  const int wcq  = tid >> 6;     // 16-channel slice
  const int l15  = lane & 15;
  const int kg   = lane >> 4;

  // B fragments in registers, once per block
  f16x8 bg[4][4];
  f16x8 bc[2];
  {
    const _Float16* wgp = WgT + (size_t)kb * (256 * 128);
#pragma unroll
    for (int g = 0; g < 4; ++g)
#pragma unroll
      for (int ks = (FIRST ? 2 : 0); ks < 4; ++ks)
        bg[g][ks] = *(const f16x8*)(wgp + (size_t)(64 * g + 16 * wcq + l15) * 128 + ks * 32 + kg * 8);
    if constexpr (!FIRST) {
      const _Float16* wcp = WcT + (size_t)kb * (64 * 64);
#pragma unroll
      for (int ks = 0; ks < 2; ++ks)
        bc[ks] = *(const f16x8*)(wcp + (size_t)(16 * wcq + l15) * 64 + ks * 32 + kg * 8);
    }
  }

  const int gr  = tid >> 3;  // staging row 0..31
  const int gq8 = tid & 7;   // 8-channel chunk
  const int srow = tid >> 3; // store row (same decomposition)
  const int sc   = tid & 7;

  auto ld_jp = [&](int tt) -> int2 {
    int grow = tt * TM + gr;
    bool v = (tt < ntiles) && (grow < cnt);
    int2 jp = op[off + min(grow, cnt - 1)];   // clamped, always valid
    if (!v) jp.x = -1;
    return jp;
  };

  // named 2-deep staging sets
  float4 xA0{}, xA1{}; f16x8 hA{}, cA{}, xA{}; int jA = -1;
  float4 xB0{}, xB1{}; f16x8 hB{}, cB{}, xB{}; int jB = -1;
  int2 jpP;

  auto rows_into = [&](int2 jp, float4& rx0, float4& rx1,
                       f16x8& rh, f16x8& rc, f16x8& rx, int& rj) {
    int p = jp.y;
    if constexpr (FIRST) {
      const float4* xr = (const float4*)(xf32 + (size_t)p * 64 + gq8 * 8);
      rx0 = xr[0]; rx1 = xr[1];
    } else {
      const _Float16* r_ = hc_in + (size_t)p * 192 + gq8 * 8;  // [h|c|x] row
      rh = *(const f16x8*)(r_);
      rc = *(const f16x8*)(r_ + 64);
      rx = *(const f16x8*)(r_ + 128);
    }
    rj = jp.x;
  };

  // prologue: stage tiles bi, bi+bpk; prefetch idx of bi+2*bpk
  rows_into(ld_jp(bi), xA0, xA1, hA, cA, xA, jA);
  rows_into(ld_jp(bi + bpk), xB0, xB1, hB, cB, xB, jB);
  jpP = ld_jp(bi + 2 * bpk);

#define HALF_STEP(TCUR, RX0, RX1, RH, RC, RX16, RJ)                             \
  {                                                                             \
    asm volatile("s_barrier" ::: "memory");   /* O-reads + A-reads done */      \
    if (gq8 == 0) jidx[gr] = RJ;                                                \
    if constexpr (FIRST) {                                                      \
      *(f16x8*)&A[gr][64 + gq8 * 8] = to_h8(RX0, RX1);                          \
    } else {                                                                    \
      *(f16x8*)&A[gr][64 + gq8 * 8] = RX16;                                     \
      *(f16x8*)&A[gr][gq8 * 8]  = RH;                                           \
      *(f16x8*)&Cg[gr][gq8 * 8] = RC;                                           \
    }                                                                           \
    asm volatile("s_waitcnt lgkmcnt(0)\n\ts_barrier" ::: "memory");             \
    /* prefetch x_next[j] for the store phase (hidden under MFMA) */            \
    float4 xn0{}, xn1{};                                                        \
    int j_st = -1;                                                              \
    if constexpr (!LAST) {                                                      \
      j_st = jidx[srow];                                                        \
      if (j_st >= 0) {                                                          \
        const float4* xn = (const float4*)(xnext + (size_t)j_st * 64 + sc * 8); \
        xn0 = xn[0]; xn1 = xn[1];                                               \
      }                                                                         \
    }                                                                           \
    rows_into(jpP, RX0, RX1, RH, RC, RX16, RJ);  /* stage rows((TCUR)+2*bpk) */ \
    jpP = ld_jp((TCUR) + 3 * bpk);                                              \
    f32x4 aG[2][4];                                                             \
    f32x4 aC[2];                                                                \
    _Pragma("unroll")                                                           \
    for (int rf = 0; rf < 2; ++rf) {                                            \
      _Pragma("unroll")                                                         \
      for (int g = 0; g < 4; ++g) aG[rf][g] = f32x4{0.f, 0.f, 0.f, 0.f};        \
      aC[rf] = f32x4{0.f, 0.f, 0.f, 0.f};                                       \
    }                                                                           \
    _Pragma("unroll")                                                           \
    for (int ks = (FIRST ? 2 : 0); ks < 4; ++ks) {                              \
      _Pragma("unroll")                                                         \
      for (int rf = 0; rf < 2; ++rf) {                                          \
        f16x8 a = *(const f16x8*)&A[16 * rf + l15][ks * 32 + kg * 8];           \
        aG[rf][0] = __builtin_amdgcn_mfma_f32_16x16x32_f16(a, bg[0][ks], aG[rf][0], 0, 0, 0); \
        aG[rf][1] = __builtin_amdgcn_mfma_f32_16x16x32_f16(a, bg[1][ks], aG[rf][1], 0, 0, 0); \
        aG[rf][2] = __builtin_amdgcn_mfma_f32_16x16x32_f16(a, bg[2][ks], aG[rf][2], 0, 0, 0); \
        aG[rf][3] = __builtin_amdgcn_mfma_f32_16x16x32_f16(a, bg[3][ks], aG[rf][3], 0, 0, 0); \
      }                                                                         \
    }                                                                           \
    if constexpr (!FIRST) {                                                     \
      _Pragma("unroll")                                                         \
      for (int ks = 0; ks < 2; ++ks) {                                          \
        _Pragma("unroll")                                                       \
        for (int rf = 0; rf < 2; ++rf) {                                        \
          f16x8 a = *(const f16x8*)&Cg[16 * rf + l15][ks * 32 + kg * 8];        \
          aC[rf] = __builtin_amdgcn_mfma_f32_16x16x32_f16(a, bc[ks], aC[rf], 0, 0, 0); \
        }                                                                       \
      }                                                                         \
    }                                                                           \
    /* epilogue -> LDS O-buffer */                                              \
    _Pragma("unroll")                                                           \
    for (int rf = 0; rf < 2; ++rf) {                                            \
      _Pragma("unroll")                                                         \
      for (int r = 0; r < 4; ++r) {                                             \
        int row = 16 * rf + kg * 4 + r;   /* C/D: row=(lane>>4)*4+reg */        \
        float ing = fsig(aG[rf][0][r]);                                         \
        float fg  = fsig(aG[rf][1][r]);                                         \
        float cgt = fsig(aG[rf][2][r]);   /* reference: sigmoid cell gate */    \
        float og  = fsig(aG[rf][3][r]);                                         \
        float cup = FIRST ? 0.0f : aC[rf][r];                                   \
        float cxv = fg * cup + ing * cgt;                                       \
        float hxv = og * ftanh_(cxv);                                           \
        int ch = 16 * wcq + l15;                                                \
        if constexpr (LAST) {                                                   \
          O32[row][ch] = hxv;                                                   \
        } else {                                                                \
          Oh[row][ch] = (_Float16)hxv;                                          \
          Oc[row][ch] = (_Float16)cxv;                                          \
        }                                                                       \
      }                                                                         \
    }                                                                           \
    asm volatile("s_waitcnt lgkmcnt(0)\n\ts_barrier" ::: "memory");             \
    /* coalesced store: 8 threads/row stream contiguous segments */             \
    if constexpr (LAST) {                                                       \
      int j = jidx[srow];                                                       \
      if (j >= 0) {                                                             \
        f32x4 v0 = *(const f32x4*)&O32[srow][sc * 8];                           \
        f32x4 v1 = *(const f32x4*)&O32[srow][sc * 8 + 4];                       \
        float* dst = out32 + (size_t)j * 64 + sc * 8;                           \
        *(f32x4*)dst = v0;                                                      \
        *(f32x4*)(dst + 4) = v1;                                                \
      }                                                                         \
    } else {                                                                    \
      if (j_st >= 0) {                                                          \
        f16x8 vh = *(const f16x8*)&Oh[srow][sc * 8];                            \
        f16x8 vc = *(const f16x8*)&Oc[srow][sc * 8];                            \
        _Float16* dst = hc_out + (size_t)j_st * 192 + sc * 8;                   \
        *(f16x8*)dst = vh;                                                      \
        *(f16x8*)(dst + 64) = vc;                                               \
        *(f16x8*)(dst + 128) = to_h8(xn0, xn1);                                 \
      }                                                                         \
    }                                                                           \
  }

  for (int t = bi; t < ntiles; t += 2 * bpk) {
    HALF_STEP(t, xA0, xA1, hA, cA, xA, jA);
    if (t + bpk < ntiles) {
      HALF_STEP(t + bpk, xB0, xB1, hB, cB, xB, jB);
    }
  }
#undef HALF_STEP
}

static inline int idiv_up(int a, int b) { return (a + b - 1) / b; }

template <bool FIRST, bool LAST>
static void run_step(const float* xf32, const _Float16* hc_in, const float* xnext,
                     const int2* op, int nout, const int* counts, int cap,
                     const _Float16* WgT, const _Float16* WcT,
                     float* out32, _Float16* hc_out, hipStream_t stream) {
  int bpk = idiv_up(nout, KNUM * TM);
  if (bpk > 160) bpk = 160;   // ~5 blocks/CU
  if (bpk < 1) bpk = 1;
  lstm_step_kernel<FIRST, LAST><<<dim3(KNUM * bpk), dim3(STEP_THREADS), 0, stream>>>(
      xf32, hc_in, xnext, op, counts, cap, WgT, WcT, out32, hc_out, bpk);
}

extern "C" void kernel_launch(void* const* d_in, const int* in_sizes, int n_in,
                              void* d_out, int out_size, void* d_ws, size_t ws_size,
                              hipStream_t stream) {
  const float* x0 = (const float*)d_in[0];
  const float* x1 = (const float*)d_in[1];
  const float* x2 = (const float*)d_in[2];
  const float* Wi = (const float*)d_in[3];
  const float* Wh = (const float*)d_in[4];
  const float* Wc = (const float*)d_in[5];
  const int* parent0 = (const int*)d_in[6];
  const int* kofs0   = (const int*)d_in[7];
  const int* parent1 = (const int*)d_in[8];
  const int* kofs1   = (const int*)d_in[9];
  const int* parent2 = (const int*)d_in[10];
  const int* kofs2   = (const int*)d_in[11];
  const int N1 = in_sizes[6];
  const int N2 = in_sizes[8];
  const int N3 = in_sizes[10];

  const int cap0 = idiv_up(N1, KNUM) + N1 / 32 + 256;
  const int cap1 = idiv_up(N2, KNUM) + N2 / 32 + 256;
  const int cap2 = idiv_up(N3, KNUM) + N3 / 32 + 256;
  const int nb0 = idiv_up(N1, 256), nb1 = idiv_up(N2, 256), nb2 = idiv_up(N3, 256);

  char* w = (char*)d_ws;
  auto carve = [&](size_t bytes) {
    char* p = w;
    w += (bytes + 255) & ~(size_t)255;
    return p;
  };
  _Float16* WgT = (_Float16*)carve((size_t)KNUM * 256 * 128 * 2);
  _Float16* WcT = (_Float16*)carve((size_t)KNUM * 64 * 64 * 2);
  int* cursor   = (int*)carve(3 * KNUM * sizeof(int));
  int2* op0     = (int2*)carve((size_t)KNUM * cap0 * sizeof(int2));
  int2* op1     = (int2*)carve((size_t)KNUM * cap1 * sizeof(int2));
  int2* op2     = (int2*)carve((size_t)KNUM * cap2 * sizeof(int2));
  _Float16* hc_a = (_Float16*)carve((size_t)N1 * 192 * 2);  // [h|c|x1] rows
  _Float16* hc_b = (_Float16*)carve((size_t)N2 * 192 * 2);  // [h|c|x2] rows
  (void)ws_size; (void)n_in; (void)out_size;

  hipMemsetAsync(cursor, 0, 3 * KNUM * sizeof(int), stream);
  prep_w_kernel<<<256, 256, 0, stream>>>(Wi, Wh, Wc, WgT, WcT);
  scatter_all_kernel<<<nb0 + nb1 + nb2, 256, 0, stream>>>(
      kofs0, parent0, N1, op0, cap0,
      kofs1, parent1, N2, op1, cap1,
      kofs2, parent2, N3, op2, cap2,
      cursor, nb0, nb1);

  run_step<true, false>(x0, nullptr, x1, op0, N1, cursor + 0 * KNUM, cap0,
                        WgT, WcT, nullptr, hc_a, stream);
  run_step<false, false>(nullptr, hc_a, x2, op1, N2, cursor + 1 * KNUM, cap1,
                         WgT, WcT, nullptr, hc_b, stream);
  run_step<false, true>(nullptr, hc_b, nullptr, op2, N3, cursor + 2 * KNUM, cap2,
                        WgT, WcT, (float*)d_out, nullptr, stream);
}

// Round 11
// 103.876 us; speedup vs baseline: 1.1066x; 1.1066x over previous
//
#include <hip/hip_runtime.h>

// Sparse generative transposed-conv LSTM decoder (3 timesteps).
// R11: R9 structure (best: 104.8us) + prep_w fused into the scatter dispatch
// (blocks 512..575 transpose weights) + s_setprio around MFMA.
// Dispatches: memset(96B), scatter+prep, 3x step = 5.

#define KNUM 8
#define TM 32
#define STEP_THREADS 256

typedef __attribute__((ext_vector_type(8))) _Float16 f16x8;
typedef __attribute__((ext_vector_type(4))) float f32x4;

__device__ __forceinline__ float fsig(float x) {
  return __builtin_amdgcn_rcpf(1.0f + __expf(-x));
}
__device__ __forceinline__ float ftanh_(float x) {
  float e = __expf(2.0f * x);
  return 1.0f - 2.0f * __builtin_amdgcn_rcpf(e + 1.0f);
}
__device__ __forceinline__ f16x8 to_h8(float4 a, float4 b) {
  f16x8 r;
  r[0] = (_Float16)a.x; r[1] = (_Float16)a.y; r[2] = (_Float16)a.z; r[3] = (_Float16)a.w;
  r[4] = (_Float16)b.x; r[5] = (_Float16)b.y; r[6] = (_Float16)b.z; r[7] = (_Float16)b.w;
  return r;
}

// ---- fused scatter + weight-prep ----
// blocks [0,512): scatter into over-allocated k-bucket regions (R9 scheme);
// blocks [512,576): weights transpose+cast (~2.3 MB).
__device__ __forceinline__ void seg_select(int b, int& seg, int& rb, int& nb) {
  if (b < 32)       { seg = 0; rb = b;       nb = 32;  }
  else if (b < 160) { seg = 1; rb = b - 32;  nb = 128; }
  else              { seg = 2; rb = b - 160; nb = 352; }
}

__global__ void scatter_prep_kernel(const int* __restrict__ k0, const int* __restrict__ p0, int n0,
                                    int2* __restrict__ op0, int cap0,
                                    const int* __restrict__ k1, const int* __restrict__ p1, int n1,
                                    int2* __restrict__ op1, int cap1,
                                    const int* __restrict__ k2, const int* __restrict__ p2, int n2,
                                    int2* __restrict__ op2, int cap2,
                                    int* __restrict__ cursor,
                                    const float* __restrict__ Wi, const float* __restrict__ Wh,
                                    const float* __restrict__ Wc,
                                    _Float16* __restrict__ WgT, _Float16* __restrict__ WcT) {
  if (blockIdx.x >= 512) {
    // ---- weight prep ----
    int tid = (blockIdx.x - 512) * blockDim.x + threadIdx.x;
    int stride = 64 * blockDim.x;
    // WgT[k][co][ci]: ci<64 -> W_h, else W_i (f16)
    for (int idx = tid; idx < KNUM * 256 * 128; idx += stride) {
      int k  = idx >> 15;
      int co = (idx >> 7) & 255;
      int ci = idx & 127;
      float v = (ci < 64) ? Wh[(k * 64 + ci) * 256 + co]
                          : Wi[(k * 64 + ci - 64) * 256 + co];
      WgT[idx] = (_Float16)v;
    }
    for (int idx = tid; idx < KNUM * 64 * 64; idx += stride) {
      int k  = idx >> 12;
      int co = (idx >> 6) & 63;
      int ci = idx & 63;
      WcT[idx] = (_Float16)Wc[(k * 64 + ci) * 64 + co];
    }
    return;
  }
  // ---- scatter ----
  int seg, rb, nb;
  seg_select(blockIdx.x, seg, rb, nb);
  const int* kp = seg == 0 ? k0 : seg == 1 ? k1 : k2;
  const int* pp = seg == 0 ? p0 : seg == 1 ? p1 : p2;
  int n   = seg == 0 ? n0 : seg == 1 ? n1 : n2;
  int cap = seg == 0 ? cap0 : seg == 1 ? cap1 : cap2;
  int2* op = seg == 0 ? op0 : seg == 1 ? op1 : op2;
  int* cur = cursor + seg * KNUM;

  __shared__ int h[KNUM], base[KNUM];
  if (threadIdx.x < KNUM) h[threadIdx.x] = 0;
  __syncthreads();
  int chunk = (n + nb - 1) / nb;
  int c0 = rb * chunk;
  int c1 = min(n, c0 + chunk);
  for (int i = c0 + threadIdx.x; i < c1; i += blockDim.x)
    atomicAdd(&h[kp[i]], 1);
  __syncthreads();
  if (threadIdx.x < KNUM) {
    base[threadIdx.x] = h[threadIdx.x] ? atomicAdd(&cur[threadIdx.x], h[threadIdx.x]) : 0;
    h[threadIdx.x] = 0;
  }
  __syncthreads();
  for (int i = c0 + threadIdx.x; i < c1; i += blockDim.x) {
    int k = kp[i];
    int rel = base[k] + atomicAdd(&h[k], 1);
    op[k * cap + rel] = make_int2(i, pp[i]);  // bucket order nondeterministic; output row-indexed -> deterministic
  }
}

// ---- step kernel: bare barriers, 2-deep staging, f32-x gather, LDS-coalesced stores ----
// hc rows: [h(64)|c(64)] f16 = 256 B.
template <bool FIRST, bool LAST>
__global__ __launch_bounds__(STEP_THREADS)
void lstm_step_kernel(const float* __restrict__ xf32, const _Float16* __restrict__ hc_in,
                      const int2* __restrict__ op, const int* __restrict__ counts, int cap,
                      const _Float16* __restrict__ WgT, const _Float16* __restrict__ WcT,
                      float* __restrict__ out32, _Float16* __restrict__ hc_out, int bpk) {
  __shared__ __align__(16) _Float16 A[TM][136];   // [h(0:64)|x(64:128)] + pad
  __shared__ __align__(16) _Float16 Cg[TM][72];
  __shared__ int jidx[TM];
  __shared__ __align__(16) char Obuf[9216];       // LAST: f32[32][68]; else 2x f16[32][72]
  float (*O32)[68] = (float(*)[68])Obuf;
  _Float16 (*Oh)[72] = (_Float16(*)[72])Obuf;
  _Float16 (*Oc)[72] = (_Float16(*)[72])(Obuf + 32 * 72 * 2);

  const int kb = blockIdx.x & 7;
  const int bi = blockIdx.x >> 3;
  const int cnt = counts[kb];
  const int off = kb * cap;
  const int ntiles = (cnt + TM - 1) / TM;
  if (bi >= ntiles || cnt == 0) return;

  const int tid  = threadIdx.x;
  const int lane = tid & 63;
  const int wcq  = tid >> 6;     // 16-channel slice
  const int l15  = lane & 15;
  const int kg   = lane >> 4;

  // B fragments in registers, once per block
  f16x8 bg[4][4];
  f16x8 bc[2];
  {
    const _Float16* wgp = WgT + (size_t)kb * (256 * 128);
#pragma unroll
    for (int g = 0; g < 4; ++g)
#pragma unroll
      for (int ks = (FIRST ? 2 : 0); ks < 4; ++ks)
        bg[g][ks] = *(const f16x8*)(wgp + (size_t)(64 * g + 16 * wcq + l15) * 128 + ks * 32 + kg * 8);
    if constexpr (!FIRST) {
      const _Float16* wcp = WcT + (size_t)kb * (64 * 64);
#pragma unroll
      for (int ks = 0; ks < 2; ++ks)
        bc[ks] = *(const f16x8*)(wcp + (size_t)(16 * wcq + l15) * 64 + ks * 32 + kg * 8);
    }
  }

  const int gr  = tid >> 3;  // staging row 0..31
  const int gq8 = tid & 7;   // 8-channel chunk

  auto ld_jp = [&](int tt) -> int2 {
    int grow = tt * TM + gr;
    bool v = (tt < ntiles) && (grow < cnt);
    int2 jp = op[off + min(grow, cnt - 1)];   // clamped, always valid
    if (!v) jp.x = -1;
    return jp;
  };

  // named 2-deep staging sets (x kept f32 until LDS-write)
  float4 xA0{}, xA1{}; f16x8 hA{}, cA{}; int jA = -1;
  float4 xB0{}, xB1{}; f16x8 hB{}, cB{}; int jB = -1;
  int2 jpP;

  auto rows_into = [&](int2 jp, float4& rx0, float4& rx1, f16x8& rh, f16x8& rc, int& rj) {
    int p = jp.y;
    const float4* xr = (const float4*)(xf32 + (size_t)p * 64 + gq8 * 8);
    rx0 = xr[0]; rx1 = xr[1];
    if constexpr (!FIRST) {
      const _Float16* hr = hc_in + (size_t)p * 128 + gq8 * 8;
      rh = *(const f16x8*)(hr);
      rc = *(const f16x8*)(hr + 64);
    }
    rj = jp.x;
  };

  // prologue: stage tiles bi, bi+bpk; prefetch idx of bi+2*bpk
  rows_into(ld_jp(bi), xA0, xA1, hA, cA, jA);
  rows_into(ld_jp(bi + bpk), xB0, xB1, hB, cB, jB);
  jpP = ld_jp(bi + 2 * bpk);

#define HALF_STEP(TCUR, RX0, RX1, RH, RC, RJ)                                   \
  {                                                                             \
    asm volatile("s_barrier" ::: "memory");   /* O-reads + A-reads done */      \
    if (gq8 == 0) jidx[gr] = RJ;                                                \
    *(f16x8*)&A[gr][64 + gq8 * 8] = to_h8(RX0, RX1);                            \
    if constexpr (!FIRST) {                                                     \
      *(f16x8*)&A[gr][gq8 * 8]  = RH;                                           \
      *(f16x8*)&Cg[gr][gq8 * 8] = RC;                                           \
    }                                                                           \
    asm volatile("s_waitcnt lgkmcnt(0)\n\ts_barrier" ::: "memory");             \
    rows_into(jpP, RX0, RX1, RH, RC, RJ);   /* stage rows((TCUR)+2*bpk) */      \
    jpP = ld_jp((TCUR) + 3 * bpk);                                              \
    f32x4 aG[2][4];                                                             \
    f32x4 aC[2];                                                                \
    _Pragma("unroll")                                                           \
    for (int rf = 0; rf < 2; ++rf) {                                            \
      _Pragma("unroll")                                                         \
      for (int g = 0; g < 4; ++g) aG[rf][g] = f32x4{0.f, 0.f, 0.f, 0.f};        \
      aC[rf] = f32x4{0.f, 0.f, 0.f, 0.f};                                       \
    }                                                                           \
    __builtin_amdgcn_s_setprio(1);                                              \
    _Pragma("unroll")                                                           \
    for (int ks = (FIRST ? 2 : 0); ks < 4; ++ks) {                              \
      _Pragma("unroll")                                                         \
      for (int rf = 0; rf < 2; ++rf) {                                          \
        f16x8 a = *(const f16x8*)&A[16 * rf + l15][ks * 32 + kg * 8];           \
        aG[rf][0] = __builtin_amdgcn_mfma_f32_16x16x32_f16(a, bg[0][ks], aG[rf][0], 0, 0, 0); \
        aG[rf][1] = __builtin_amdgcn_mfma_f32_16x16x32_f16(a, bg[1][ks], aG[rf][1], 0, 0, 0); \
        aG[rf][2] = __builtin_amdgcn_mfma_f32_16x16x32_f16(a, bg[2][ks], aG[rf][2], 0, 0, 0); \
        aG[rf][3] = __builtin_amdgcn_mfma_f32_16x16x32_f16(a, bg[3][ks], aG[rf][3], 0, 0, 0); \
      }                                                                         \
    }                                                                           \
    if constexpr (!FIRST) {                                                     \
      _Pragma("unroll")                                                         \
      for (int ks = 0; ks < 2; ++ks) {                                          \
        _Pragma("unroll")                                                       \
        for (int rf = 0; rf < 2; ++rf) {                                        \
          f16x8 a = *(const f16x8*)&Cg[16 * rf + l15][ks * 32 + kg * 8];        \
          aC[rf] = __builtin_amdgcn_mfma_f32_16x16x32_f16(a, bc[ks], aC[rf], 0, 0, 0); \
        }                                                                       \
      }                                                                         \
    }                                                                           \
    __builtin_amdgcn_s_setprio(0);                                              \
    /* epilogue -> LDS O-buffer */                                              \
    _Pragma("unroll")                                                           \
    for (int rf = 0; rf < 2; ++rf) {                                            \
      _Pragma("unroll")                                                         \
      for (int r = 0; r < 4; ++r) {                                             \
        int row = 16 * rf + kg * 4 + r;   /* C/D: row=(lane>>4)*4+reg */        \
        float ing = fsig(aG[rf][0][r]);                                         \
        float fg  = fsig(aG[rf][1][r]);                                         \
        float cgt = fsig(aG[rf][2][r]);   /* reference: sigmoid cell gate */    \
        float og  = fsig(aG[rf][3][r]);                                         \
        float cup = FIRST ? 0.0f : aC[rf][r];                                   \
        float cxv = fg * cup + ing * cgt;                                       \
        float hxv = og * ftanh_(cxv);                                           \
        int ch = 16 * wcq + l15;                                                \
        if constexpr (LAST) {                                                   \
          O32[row][ch] = hxv;                                                   \
        } else {                                                                \
          Oh[row][ch] = (_Float16)hxv;                                          \
          Oc[row][ch] = (_Float16)cxv;                                          \
        }                                                                       \
      }                                                                         \
    }                                                                           \
    asm volatile("s_waitcnt lgkmcnt(0)\n\ts_barrier" ::: "memory");             \
    /* coalesced store: 8 threads/row stream contiguous segments */             \
    {                                                                           \
      int srow = tid >> 3, sc = tid & 7;                                        \
      int j = jidx[srow];                                                       \
      if (j >= 0) {                                                             \
        if constexpr (LAST) {                                                   \
          f32x4 v0 = *(const f32x4*)&O32[srow][sc * 8];                         \
          f32x4 v1 = *(const f32x4*)&O32[srow][sc * 8 + 4];                     \
          float* dst = out32 + (size_t)j * 64 + sc * 8;                         \
          *(f32x4*)dst = v0;                                                    \
          *(f32x4*)(dst + 4) = v1;                                              \
        } else {                                                                \
          f16x8 vh = *(const f16x8*)&Oh[srow][sc * 8];                          \
          f16x8 vc = *(const f16x8*)&Oc[srow][sc * 8];                          \
          _Float16* dst = hc_out + (size_t)j * 128 + sc * 8;                    \
          *(f16x8*)dst = vh;                                                    \
          *(f16x8*)(dst + 64) = vc;                                             \
        }                                                                       \
      }                                                                         \
    }                                                                           \
  }

  for (int t = bi; t < ntiles; t += 2 * bpk) {
    HALF_STEP(t, xA0, xA1, hA, cA, jA);
    if (t + bpk < ntiles) {
      HALF_STEP(t + bpk, xB0, xB1, hB, cB, jB);
    }
  }
#undef HALF_STEP
}

static inline int idiv_up(int a, int b) { return (a + b - 1) / b; }

template <bool FIRST, bool LAST>
static void run_step(const float* xf32, const _Float16* hc_in,
                     const int2* op, int nout, const int* counts, int cap,
                     const _Float16* WgT, const _Float16* WcT,
                     float* out32, _Float16* hc_out, hipStream_t stream) {
  int bpk = idiv_up(nout, KNUM * TM);
  if (bpk > 160) bpk = 160;   // 5 blocks/CU
  if (bpk < 1) bpk = 1;
  lstm_step_kernel<FIRST, LAST><<<dim3(KNUM * bpk), dim3(STEP_THREADS), 0, stream>>>(
      xf32, hc_in, op, counts, cap, WgT, WcT, out32, hc_out, bpk);
}

extern "C" void kernel_launch(void* const* d_in, const int* in_sizes, int n_in,
                              void* d_out, int out_size, void* d_ws, size_t ws_size,
                              hipStream_t stream) {
  const float* x0 = (const float*)d_in[0];
  const float* x1 = (const float*)d_in[1];
  const float* x2 = (const float*)d_in[2];
  const float* Wi = (const float*)d_in[3];
  const float* Wh = (const float*)d_in[4];
  const float* Wc = (const float*)d_in[5];
  const int* parent0 = (const int*)d_in[6];
  const int* kofs0   = (const int*)d_in[7];
  const int* parent1 = (const int*)d_in[8];
  const int* kofs1   = (const int*)d_in[9];
  const int* parent2 = (const int*)d_in[10];
  const int* kofs2   = (const int*)d_in[11];
  const int N1 = in_sizes[6];
  const int N2 = in_sizes[8];
  const int N3 = in_sizes[10];

  const int cap0 = idiv_up(N1, KNUM) + N1 / 32 + 256;
  const int cap1 = idiv_up(N2, KNUM) + N2 / 32 + 256;
  const int cap2 = idiv_up(N3, KNUM) + N3 / 32 + 256;

  char* w = (char*)d_ws;
  auto carve = [&](size_t bytes) {
    char* p = w;
    w += (bytes + 255) & ~(size_t)255;
    return p;
  };
  _Float16* WgT = (_Float16*)carve((size_t)KNUM * 256 * 128 * 2);
  _Float16* WcT = (_Float16*)carve((size_t)KNUM * 64 * 64 * 2);
  int* cursor   = (int*)carve(3 * KNUM * sizeof(int));
  int2* op0     = (int2*)carve((size_t)KNUM * cap0 * sizeof(int2));
  int2* op1     = (int2*)carve((size_t)KNUM * cap1 * sizeof(int2));
  int2* op2     = (int2*)carve((size_t)KNUM * cap2 * sizeof(int2));
  _Float16* hc_a = (_Float16*)carve((size_t)N1 * 128 * 2);  // [h|c] rows
  _Float16* hc_b = (_Float16*)carve((size_t)N2 * 128 * 2);
  (void)ws_size; (void)n_in; (void)out_size;

  hipMemsetAsync(cursor, 0, 3 * KNUM * sizeof(int), stream);
  scatter_prep_kernel<<<576, 256, 0, stream>>>(kofs0, parent0, N1, op0, cap0,
                                               kofs1, parent1, N2, op1, cap1,
                                               kofs2, parent2, N3, op2, cap2,
                                               cursor, Wi, Wh, Wc, WgT, WcT);

  run_step<true, false>(x0, nullptr, op0, N1, cursor + 0 * KNUM, cap0,
                        WgT, WcT, nullptr, hc_a, stream);
  run_step<false, false>(x1, hc_a, op1, N2, cursor + 1 * KNUM, cap1,
                         WgT, WcT, nullptr, hc_b, stream);
  run_step<false, true>(x2, hc_b, op2, N3, cursor + 2 * KNUM, cap2,
                        WgT, WcT, (float*)d_out, nullptr, stream);
}